// Round 1
// baseline (267.533 us; speedup 1.0000x reference)
//
#include <hip/hip_runtime.h>

// FTScanBasic: inclusive cumsum along axis 0 of xs[8192][4096] fp32.
// d_out layout: [0..4095] = final carry (ys[-1]), [4096..] = ys flat.
//
// Three-pass chunked scan:
//   pass1: per-chunk column sums -> partials[CHUNKS][D] in d_ws
//   pass2: exclusive scan of partials along chunk axis (per column)
//   pass3: re-read xs, seed with exclusive offset, write inclusive rows.

constexpr int T_ROWS = 8192;
constexpr int D_COLS = 4096;
constexpr int D4 = D_COLS / 4;                    // 1024 float4 per row
constexpr int CHUNKS = 256;
constexpr int ROWS_PER_CHUNK = T_ROWS / CHUNKS;   // 32
constexpr int THREADS = 256;
constexpr int COL_BLOCKS = D4 / THREADS;          // 4

__global__ __launch_bounds__(THREADS)
void scan_pass1(const float4* __restrict__ xs, float4* __restrict__ partials) {
    const int col4  = blockIdx.x * THREADS + threadIdx.x;  // 0..1023 (float4 col)
    const int chunk = blockIdx.y;
    const float4* p = xs + (size_t)chunk * ROWS_PER_CHUNK * D4 + col4;
    float4 acc = make_float4(0.f, 0.f, 0.f, 0.f);
#pragma unroll
    for (int r = 0; r < ROWS_PER_CHUNK; ++r) {
        float4 v = p[(size_t)r * D4];
        acc.x += v.x; acc.y += v.y; acc.z += v.z; acc.w += v.w;
    }
    partials[(size_t)chunk * D4 + col4] = acc;
}

__global__ __launch_bounds__(256)
void scan_pass2(float* __restrict__ partials) {
    const int col = blockIdx.x * blockDim.x + threadIdx.x;  // 0..4095
    float run = 0.f;
#pragma unroll 8
    for (int c = 0; c < CHUNKS; ++c) {
        float v = partials[(size_t)c * D_COLS + col];
        partials[(size_t)c * D_COLS + col] = run;
        run += v;
    }
}

__global__ __launch_bounds__(THREADS)
void scan_pass3(const float4* __restrict__ xs, const float4* __restrict__ partials,
                float4* __restrict__ ys, float4* __restrict__ carry) {
    const int col4  = blockIdx.x * THREADS + threadIdx.x;
    const int chunk = blockIdx.y;
    const size_t base = (size_t)chunk * ROWS_PER_CHUNK * D4 + col4;
    float4 run = partials[(size_t)chunk * D4 + col4];
#pragma unroll
    for (int r = 0; r < ROWS_PER_CHUNK; ++r) {
        float4 v = xs[base + (size_t)r * D4];
        run.x += v.x; run.y += v.y; run.z += v.z; run.w += v.w;
        ys[base + (size_t)r * D4] = run;
    }
    if (chunk == CHUNKS - 1) {
        carry[col4] = run;   // run == inclusive sum of all T rows
    }
}

extern "C" void kernel_launch(void* const* d_in, const int* in_sizes, int n_in,
                              void* d_out, int out_size, void* d_ws, size_t ws_size,
                              hipStream_t stream) {
    const float4* xs = (const float4*)d_in[0];
    float* out = (float*)d_out;
    float4* carry = (float4*)out;                 // first 4096 floats
    float4* ys = (float4*)(out + D_COLS);         // ys starts at 16 KiB offset (16B-aligned)
    float4* partials = (float4*)d_ws;             // CHUNKS * D_COLS * 4 B = 4 MiB

    dim3 grid13(COL_BLOCKS, CHUNKS);              // 4 x 256 = 1024 blocks
    scan_pass1<<<grid13, THREADS, 0, stream>>>(xs, partials);
    scan_pass2<<<D_COLS / 256, 256, 0, stream>>>((float*)d_ws);
    scan_pass3<<<grid13, THREADS, 0, stream>>>(xs, partials, ys, carry);
}

// Round 2
// 251.340 us; speedup vs baseline: 1.0644x; 1.0644x over previous
//
#include <hip/hip_runtime.h>

// FTScanBasic: inclusive cumsum along axis 0 of xs[8192][4096] fp32.
// d_out layout: [0..4095] = final carry (ys[-1]), [4096..] = ys flat.
//
// Two-pass chunked scan (no serial pass2, no atomics):
//   pass1: per-chunk column sums -> partials[CHUNKS][D4] (float4) in d_ws
//   pass2: each block sums its <chunk predecessor partial rows itself
//          (coalesced, independent loads, L2/LLC-hot), then streams its
//          chunk: run += x, write inclusive row. Chunk 127 writes carry.

constexpr int T_ROWS = 8192;
constexpr int D_COLS = 4096;
constexpr int D4 = D_COLS / 4;          // 1024 float4 per row
constexpr int CHUNKS = 128;
constexpr int RPC = T_ROWS / CHUNKS;    // 64 rows per chunk
constexpr int THREADS = 256;
constexpr int COL_BLOCKS = D4 / THREADS; // 4

__device__ __forceinline__ void acc4(float4& a, const float4& v) {
    a.x += v.x; a.y += v.y; a.z += v.z; a.w += v.w;
}

__global__ __launch_bounds__(THREADS)
void scan_pass1(const float4* __restrict__ xs, float4* __restrict__ partials) {
    const int col4  = blockIdx.x * THREADS + threadIdx.x;  // 0..1023
    const int chunk = blockIdx.y;
    const float4* p = xs + (size_t)chunk * RPC * D4 + col4;
    float4 acc = make_float4(0.f, 0.f, 0.f, 0.f);
#pragma unroll 8
    for (int r = 0; r < RPC; ++r) {
        acc4(acc, p[(size_t)r * D4]);
    }
    partials[(size_t)chunk * D4 + col4] = acc;
}

__global__ __launch_bounds__(THREADS)
void scan_pass2(const float4* __restrict__ xs, const float4* __restrict__ partials,
                float4* __restrict__ ys, float4* __restrict__ carry) {
    const int col4  = blockIdx.x * THREADS + threadIdx.x;
    const int chunk = blockIdx.y;

    // Exclusive prefix for this chunk: sum predecessor partial rows directly.
    // <=127 independent coalesced loads from L2/LLC; pipelined by unroll.
    float4 run = make_float4(0.f, 0.f, 0.f, 0.f);
#pragma unroll 4
    for (int c = 0; c < chunk; ++c) {
        acc4(run, partials[(size_t)c * D4 + col4]);
    }

    // Stream this chunk: inclusive scan.
    const size_t base = (size_t)chunk * RPC * D4 + col4;
#pragma unroll 8
    for (int r = 0; r < RPC; ++r) {
        acc4(run, xs[base + (size_t)r * D4]);
        ys[base + (size_t)r * D4] = run;
    }

    if (chunk == CHUNKS - 1) {
        carry[col4] = run;   // inclusive sum of all T rows
    }
}

extern "C" void kernel_launch(void* const* d_in, const int* in_sizes, int n_in,
                              void* d_out, int out_size, void* d_ws, size_t ws_size,
                              hipStream_t stream) {
    const float4* xs = (const float4*)d_in[0];
    float* out = (float*)d_out;
    float4* carry = (float4*)out;                 // first 4096 floats
    float4* ys = (float4*)(out + D_COLS);         // 16 KiB offset, 16B-aligned
    float4* partials = (float4*)d_ws;             // CHUNKS * D4 * 16 B = 2 MiB

    dim3 grid(COL_BLOCKS, CHUNKS);                // 4 x 128 = 512 blocks
    scan_pass1<<<grid, THREADS, 0, stream>>>(xs, partials);
    scan_pass2<<<grid, THREADS, 0, stream>>>(xs, partials, ys, carry);
}